// Round 1
// baseline (38.378 us; speedup 1.0000x reference)
//
#include <hip/hip_runtime.h>
#include <hip/hip_bf16.h>
#include <math.h>

#define SPLIT 8

constexpr float QMIN = 0.1f;
constexpr float SB_ = 1.0f;
constexpr float EPS = 0.001f;   // EPS_LSE

// ---------------- Kernel A: per-point beta transform + noise sums ----------
__global__ __launch_bounds__(256) void prep_kernel(
    const float* __restrict__ beta, const int* __restrict__ asso,
    const int* __restrict__ rowidx, float* __restrict__ bs,
    float* __restrict__ pl, float* __restrict__ noise, int N) {
  __shared__ float snoise[16];
  if (threadIdx.x < 16) snoise[threadIdx.x] = 0.f;
  __syncthreads();
  int n = blockIdx.x * blockDim.x + threadIdx.x;
  if (n < N) {
    float b = beta[n];
    float a = atanhf(b / 1.001f);
    float p = a * a;
    pl[n] = p;
    bs[n] = p + QMIN;
    if (asso[n] < 0) atomicAdd(&snoise[rowidx[n] & 15], SB_ * b);
  }
  __syncthreads();
  if (threadIdx.x < 16) {
    float v = snoise[threadIdx.x];
    if (v != 0.f) atomicAdd(&noise[threadIdx.x], v);
  }
}

// ---------------- Kernel B: per-cluster member pass ------------------------
__global__ __launch_bounds__(256) void cluster_kernel(
    const float* __restrict__ beta, const float* __restrict__ coords,
    const float* __restrict__ bs, const float* __restrict__ pl,
    const int* __restrict__ M, int Mmax,
    float* __restrict__ k_sumV, float* __restrict__ k_cnt,
    float* __restrict__ k_bsk, float* __restrict__ k_sumpl,
    float* __restrict__ k_betapen, float* __restrict__ k_xa) {
  const int k = blockIdx.x;
  const int* Mrow = M + (long)k * Mmax;
  const int lane = threadIdx.x & 63, wid = threadIdx.x >> 6;

  // phase 1: argmax of bs over valid members (first-max tiebreak), max beta
  float bestV = -1.f; int bestI = 0x7fffffff; float maxb = 0.f;
  for (int i = threadIdx.x; i < Mmax; i += blockDim.x) {
    int idx = Mrow[i];
    if (idx >= 0) {
      float v = bs[idx];
      if (v > bestV || (v == bestV && i < bestI)) { bestV = v; bestI = i; }
      maxb = fmaxf(maxb, beta[idx]);
    }
  }
  for (int o = 32; o > 0; o >>= 1) {
    float v2 = __shfl_down(bestV, o, 64);
    int   i2 = __shfl_down(bestI, o, 64);
    float m2 = __shfl_down(maxb, o, 64);
    if (v2 > bestV || (v2 == bestV && i2 < bestI)) { bestV = v2; bestI = i2; }
    maxb = fmaxf(maxb, m2);
  }
  __shared__ float shV[4]; __shared__ int shI[4]; __shared__ float shM[4];
  __shared__ float s_xa[8]; __shared__ float s_info[2];  // bsk, maxb
  if (lane == 0) { shV[wid] = bestV; shI[wid] = bestI; shM[wid] = maxb; }
  __syncthreads();
  if (threadIdx.x == 0) {
    bestV = shV[0]; bestI = shI[0]; maxb = shM[0];
    for (int w = 1; w < 4; ++w) {
      if (shV[w] > bestV || (shV[w] == bestV && shI[w] < bestI)) { bestV = shV[w]; bestI = shI[w]; }
      maxb = fmaxf(maxb, shM[w]);
    }
    int alpha = Mrow[bestI];
    const float4* c4 = reinterpret_cast<const float4*>(coords) + (long)alpha * 2;
    float4 p0 = c4[0], p1 = c4[1];
    s_xa[0] = p0.x; s_xa[1] = p0.y; s_xa[2] = p0.z; s_xa[3] = p0.w;
    s_xa[4] = p1.x; s_xa[5] = p1.y; s_xa[6] = p1.z; s_xa[7] = p1.w;
    s_info[0] = bs[alpha];
    s_info[1] = maxb;
  }
  __syncthreads();
  float xa[8];
  #pragma unroll
  for (int c = 0; c < 8; ++c) xa[c] = s_xa[c];
  maxb = s_info[1];

  // phase 2: member sums
  float sumV = 0.f, cnt = 0.f, sumpl = 0.f, sumbeta = 0.f, sumexp = 0.f;
  for (int i = threadIdx.x; i < Mmax; i += blockDim.x) {
    int idx = Mrow[i];
    if (idx >= 0) {
      const float4* c4 = reinterpret_cast<const float4*>(coords) + (long)idx * 2;
      float4 p0 = c4[0], p1 = c4[1];
      float d0 = p0.x-xa[0], d1 = p0.y-xa[1], d2 = p0.z-xa[2], d3 = p0.w-xa[3];
      float d4 = p1.x-xa[4], d5 = p1.y-xa[5], d6 = p1.z-xa[6], d7 = p1.w-xa[7];
      float dsq = d0*d0+d1*d1+d2*d2+d3*d3+d4*d4+d5*d5+d6*d6+d7*d7;
      sumV += dsq * bs[idx];
      cnt  += 1.f;
      sumpl += pl[idx];
      float b = beta[idx];
      sumbeta += b;
      sumexp += expf((b - maxb) * (1.f / EPS));
    }
  }
  __shared__ float red[5][4];
  float vals[5] = {sumV, cnt, sumpl, sumbeta, sumexp};
  #pragma unroll
  for (int j = 0; j < 5; ++j) {
    float v = vals[j];
    for (int o = 32; o > 0; o >>= 1) v += __shfl_down(v, o, 64);
    if (lane == 0) red[j][wid] = v;
  }
  __syncthreads();
  if (threadIdx.x == 0) {
    float t[5];
    #pragma unroll
    for (int j = 0; j < 5; ++j) t[j] = red[j][0] + red[j][1] + red[j][2] + red[j][3];
    float cntT = t[1];
    float npad = (float)Mmax - cntT;                 // zero-padded lse entries
    float sumexpT = t[4] + npad * expf(-s_info[1] * (1.f / EPS));
    float lse = s_info[1] * (1.f / EPS) + logf(sumexpT);
    float sb = fminf(fmaxf(t[3], 0.f), 1.f);
    float beta_pen = 1.f - EPS * lse + (1.f - sb);
    float bsk = s_info[0];
    k_sumV[k] = t[0] * bsk;   // includes bs_k factor
    k_cnt[k] = cntT;
    k_bsk[k] = bsk;
    k_sumpl[k] = t[2];
    k_betapen[k] = beta_pen;
    #pragma unroll
    for (int c = 0; c < 8; ++c) k_xa[k * 8 + c] = s_xa[c];
  }
}

// ---------------- Kernel C: repulsion over non-members ---------------------
__global__ __launch_bounds__(256) void rep_kernel(
    const float* __restrict__ coords, const float* __restrict__ bs,
    const int* __restrict__ Mnot, const float* __restrict__ k_xa,
    int Wn, float* __restrict__ rep_part, float* __restrict__ nkn_part) {
  const int k = blockIdx.x / SPLIT;
  const int s = blockIdx.x % SPLIT;
  const int chunk = (Wn + SPLIT - 1) / SPLIT;
  const int lo = s * chunk;
  const int hi = min(Wn, lo + chunk);
  float xa[8];
  #pragma unroll
  for (int c = 0; c < 8; ++c) xa[c] = k_xa[k * 8 + c];
  const int* row = Mnot + (long)k * Wn;
  float srep = 0.f, scnt = 0.f;
  for (int i = lo + threadIdx.x; i < hi; i += blockDim.x) {
    int idx = row[i];
    if (idx >= 0) {
      scnt += 1.f;
      const float4* c4 = reinterpret_cast<const float4*>(coords) + (long)idx * 2;
      float4 p0 = c4[0], p1 = c4[1];
      float d0 = p0.x-xa[0], d1 = p0.y-xa[1], d2 = p0.z-xa[2], d3 = p0.w-xa[3];
      float d4 = p1.x-xa[4], d5 = p1.y-xa[5], d6 = p1.z-xa[6], d7 = p1.w-xa[7];
      float dsq = d0*d0+d1*d1+d2*d2+d3*d3+d4*d4+d5*d5+d6*d6+d7*d7;
      float t = dsq + 1e-6f;
      if (t < 1.f) srep += (1.f - sqrtf(t)) * bs[idx];   // bs gather only when near
    }
  }
  const int lane = threadIdx.x & 63, wid = threadIdx.x >> 6;
  __shared__ float red[2][4];
  float vals[2] = {srep, scnt};
  #pragma unroll
  for (int j = 0; j < 2; ++j) {
    float v = vals[j];
    for (int o = 32; o > 0; o >>= 1) v += __shfl_down(v, o, 64);
    if (lane == 0) red[j][wid] = v;
  }
  __syncthreads();
  if (threadIdx.x == 0) {
    rep_part[k * SPLIT + s] = red[0][0] + red[0][1] + red[0][2] + red[0][3];
    nkn_part[k * SPLIT + s] = red[1][0] + red[1][1] + red[1][2] + red[1][3];
  }
}

// ---------------- Kernel D: finalize scalars + per-k losses ----------------
__global__ __launch_bounds__(256) void finalize_kernel(
    const float* __restrict__ k_sumV, const float* __restrict__ k_cnt,
    const float* __restrict__ k_bsk, const float* __restrict__ k_betapen,
    const float* __restrict__ rep_part, const float* __restrict__ nkn_part,
    const int* __restrict__ k_per_obj, const int* __restrict__ lengths,
    const float* __restrict__ noise,
    float* __restrict__ k_LVk, float* __restrict__ k_Lrepk,
    float* __restrict__ out, int K, int B) {
  float lv = 0.f, lrep = 0.f, lb = 0.f;
  for (int k = threadIdx.x; k < K; k += blockDim.x) {
    float cnt = k_cnt[k];
    float LVk = k_sumV[k] / (cnt + 1e-6f);
    float sr = 0.f, sc = 0.f;
    for (int s = 0; s < SPLIT; ++s) { sr += rep_part[k*SPLIT+s]; sc += nkn_part[k*SPLIT+s]; }
    float Lrepk = k_bsk[k] * sr / (sc + 1e-6f);
    k_LVk[k] = LVk;
    k_Lrepk[k] = Lrepk;
    float invK = 1.f / (float)k_per_obj[k];
    lv += LVk * invK;
    lrep += Lrepk * invK;
    lb += k_betapen[k] * invK;
  }
  const int lane = threadIdx.x & 63, wid = threadIdx.x >> 6;
  __shared__ float red[3][4];
  float vals[3] = {lv, lrep, lb};
  #pragma unroll
  for (int j = 0; j < 3; ++j) {
    float v = vals[j];
    for (int o = 32; o > 0; o >>= 1) v += __shfl_down(v, o, 64);
    if (lane == 0) red[j][wid] = v;
  }
  __syncthreads();
  if (threadIdx.x == 0) {
    float lvT = red[0][0]+red[0][1]+red[0][2]+red[0][3];
    float lrT = red[1][0]+red[1][1]+red[1][2]+red[1][3];
    float lbT = red[2][0]+red[2][1]+red[2][2]+red[2][3];
    float noiseterm = 0.f;
    for (int b = 0; b < B; ++b) noiseterm += noise[b] / (float)lengths[b];
    noiseterm /= (float)B;
    out[0] = lvT;
    out[1] = lrT;
    out[2] = lbT + noiseterm;
  }
}

// ---------------- Kernel E: scatter per-point outputs ----------------------
__global__ __launch_bounds__(256) void scatter_kernel(
    const float* __restrict__ pl, const int* __restrict__ asso,
    const float* __restrict__ k_sumpl, const float* __restrict__ k_LVk,
    const float* __restrict__ k_Lrepk,
    float* __restrict__ out_pl, float* __restrict__ out_lvrep, int N) {
  int n = blockIdx.x * blockDim.x + threadIdx.x;
  if (n < N) {
    int a = asso[n];
    float op = 0.f, ol = 0.f;
    if (a >= 0) {
      op = pl[n] / (k_sumpl[a] + 1e-12f);
      ol = k_LVk[a] + k_Lrepk[a];
    }
    out_pl[n] = op;
    out_lvrep[n] = ol;
  }
}

extern "C" void kernel_launch(void* const* d_in, const int* in_sizes, int n_in,
                              void* d_out, int out_size, void* d_ws, size_t ws_size,
                              hipStream_t stream) {
  const float* beta      = (const float*)d_in[0];
  const float* coords    = (const float*)d_in[1];
  const int*   asso      = (const int*)d_in[2];
  const int*   M         = (const int*)d_in[3];
  const int*   Mnot      = (const int*)d_in[4];
  const int*   k_per_obj = (const int*)d_in[5];
  const int*   rowidx    = (const int*)d_in[6];
  const int*   lengths   = (const int*)d_in[7];

  const int N    = in_sizes[0];
  const int K    = in_sizes[5];
  const int Mmax = in_sizes[3] / K;
  const int Wn   = in_sizes[4] / K;
  const int B    = in_sizes[7];

  float* ws        = (float*)d_ws;
  float* bs        = ws;                    // N
  float* pl        = bs + N;                // N
  float* k_sumV    = pl + N;                // K
  float* k_cnt     = k_sumV + K;            // K
  float* k_bsk     = k_cnt + K;             // K
  float* k_sumpl   = k_bsk + K;             // K
  float* k_betapen = k_sumpl + K;           // K
  float* k_xa      = k_betapen + K;         // K*8
  float* rep_part  = k_xa + K * 8;          // K*SPLIT
  float* nkn_part  = rep_part + K * SPLIT;  // K*SPLIT
  float* k_LVk     = nkn_part + K * SPLIT;  // K
  float* k_Lrepk   = k_LVk + K;             // K
  float* noise     = k_Lrepk + K;           // 16

  float* out       = (float*)d_out;
  float* out_pl    = out + 3;
  float* out_lvrep = out + 3 + N;

  hipMemsetAsync(noise, 0, 16 * sizeof(float), stream);

  int nb = (N + 255) / 256;
  prep_kernel<<<nb, 256, 0, stream>>>(beta, asso, rowidx, bs, pl, noise, N);
  cluster_kernel<<<K, 256, 0, stream>>>(beta, coords, bs, pl, M, Mmax,
                                        k_sumV, k_cnt, k_bsk, k_sumpl, k_betapen, k_xa);
  rep_kernel<<<K * SPLIT, 256, 0, stream>>>(coords, bs, Mnot, k_xa, Wn, rep_part, nkn_part);
  finalize_kernel<<<1, 256, 0, stream>>>(k_sumV, k_cnt, k_bsk, k_betapen, rep_part, nkn_part,
                                         k_per_obj, lengths, noise, k_LVk, k_Lrepk, out, K, B);
  scatter_kernel<<<nb, 256, 0, stream>>>(pl, asso, k_sumpl, k_LVk, k_Lrepk, out_pl, out_lvrep, N);
}

// Round 2
// 34.582 us; speedup vs baseline: 1.1098x; 1.1098x over previous
//
#include <hip/hip_runtime.h>
#include <hip/hip_bf16.h>
#include <math.h>

#define SPLIT 8

constexpr float QMIN = 0.1f;
constexpr float SB_ = 1.0f;
constexpr float EPS = 0.001f;   // EPS_LSE

// ---------------- Kernel A: per-point beta transform + noise sums ----------
__global__ __launch_bounds__(256) void prep_kernel(
    const float* __restrict__ beta, const int* __restrict__ asso,
    const int* __restrict__ rowidx, float* __restrict__ bs,
    float* __restrict__ pl, float* __restrict__ noise, int N) {
  __shared__ float snoise[16];
  if (threadIdx.x < 16) snoise[threadIdx.x] = 0.f;
  __syncthreads();
  int n = blockIdx.x * blockDim.x + threadIdx.x;
  if (n < N) {
    float b = beta[n];
    float a = atanhf(b / 1.001f);
    float p = a * a;
    pl[n] = p;
    bs[n] = p + QMIN;
    if (asso[n] < 0) atomicAdd(&snoise[rowidx[n] & 15], SB_ * b);
  }
  __syncthreads();
  if (threadIdx.x < 16) {
    float v = snoise[threadIdx.x];
    if (v != 0.f) atomicAdd(&noise[threadIdx.x], v);
  }
}

// ---------------- Kernel B: per-cluster member pass ------------------------
__global__ __launch_bounds__(256) void cluster_kernel(
    const float* __restrict__ beta, const float* __restrict__ coords,
    const float* __restrict__ bs, const float* __restrict__ pl,
    const int* __restrict__ M, int Mmax,
    float* __restrict__ k_sumV, float* __restrict__ k_cnt,
    float* __restrict__ k_bsk, float* __restrict__ k_sumpl,
    float* __restrict__ k_betapen, float* __restrict__ k_xa) {
  const int k = blockIdx.x;
  const int* Mrow = M + (long)k * Mmax;
  const int lane = threadIdx.x & 63, wid = threadIdx.x >> 6;

  // phase 1: argmax of bs over valid members (first-max tiebreak), max beta
  float bestV = -1.f; int bestI = 0x7fffffff; float maxb = 0.f;
  for (int i = threadIdx.x; i < Mmax; i += blockDim.x) {
    int idx = Mrow[i];
    if (idx >= 0) {
      float v = bs[idx];
      if (v > bestV || (v == bestV && i < bestI)) { bestV = v; bestI = i; }
      maxb = fmaxf(maxb, beta[idx]);
    }
  }
  for (int o = 32; o > 0; o >>= 1) {
    float v2 = __shfl_down(bestV, o, 64);
    int   i2 = __shfl_down(bestI, o, 64);
    float m2 = __shfl_down(maxb, o, 64);
    if (v2 > bestV || (v2 == bestV && i2 < bestI)) { bestV = v2; bestI = i2; }
    maxb = fmaxf(maxb, m2);
  }
  __shared__ float shV[4]; __shared__ int shI[4]; __shared__ float shM[4];
  __shared__ float s_xa[8]; __shared__ float s_info[2];  // bsk, maxb
  if (lane == 0) { shV[wid] = bestV; shI[wid] = bestI; shM[wid] = maxb; }
  __syncthreads();
  if (threadIdx.x == 0) {
    bestV = shV[0]; bestI = shI[0]; maxb = shM[0];
    for (int w = 1; w < 4; ++w) {
      if (shV[w] > bestV || (shV[w] == bestV && shI[w] < bestI)) { bestV = shV[w]; bestI = shI[w]; }
      maxb = fmaxf(maxb, shM[w]);
    }
    int alpha = Mrow[bestI];
    const float4* c4 = reinterpret_cast<const float4*>(coords) + (long)alpha * 2;
    float4 p0 = c4[0], p1 = c4[1];
    s_xa[0] = p0.x; s_xa[1] = p0.y; s_xa[2] = p0.z; s_xa[3] = p0.w;
    s_xa[4] = p1.x; s_xa[5] = p1.y; s_xa[6] = p1.z; s_xa[7] = p1.w;
    s_info[0] = bs[alpha];
    s_info[1] = maxb;
  }
  __syncthreads();
  float xa[8];
  #pragma unroll
  for (int c = 0; c < 8; ++c) xa[c] = s_xa[c];
  maxb = s_info[1];

  // phase 2: member sums
  float sumV = 0.f, cnt = 0.f, sumpl = 0.f, sumbeta = 0.f, sumexp = 0.f;
  for (int i = threadIdx.x; i < Mmax; i += blockDim.x) {
    int idx = Mrow[i];
    if (idx >= 0) {
      const float4* c4 = reinterpret_cast<const float4*>(coords) + (long)idx * 2;
      float4 p0 = c4[0], p1 = c4[1];
      float d0 = p0.x-xa[0], d1 = p0.y-xa[1], d2 = p0.z-xa[2], d3 = p0.w-xa[3];
      float d4 = p1.x-xa[4], d5 = p1.y-xa[5], d6 = p1.z-xa[6], d7 = p1.w-xa[7];
      float dsq = d0*d0+d1*d1+d2*d2+d3*d3+d4*d4+d5*d5+d6*d6+d7*d7;
      sumV += dsq * bs[idx];
      cnt  += 1.f;
      sumpl += pl[idx];
      float b = beta[idx];
      sumbeta += b;
      sumexp += expf((b - maxb) * (1.f / EPS));
    }
  }
  __shared__ float red[5][4];
  float vals[5] = {sumV, cnt, sumpl, sumbeta, sumexp};
  #pragma unroll
  for (int j = 0; j < 5; ++j) {
    float v = vals[j];
    for (int o = 32; o > 0; o >>= 1) v += __shfl_down(v, o, 64);
    if (lane == 0) red[j][wid] = v;
  }
  __syncthreads();
  if (threadIdx.x == 0) {
    float t[5];
    #pragma unroll
    for (int j = 0; j < 5; ++j) t[j] = red[j][0] + red[j][1] + red[j][2] + red[j][3];
    float cntT = t[1];
    float npad = (float)Mmax - cntT;                 // zero-padded lse entries
    float sumexpT = t[4] + npad * expf(-s_info[1] * (1.f / EPS));
    float lse = s_info[1] * (1.f / EPS) + logf(sumexpT);
    float sb = fminf(fmaxf(t[3], 0.f), 1.f);
    float beta_pen = 1.f - EPS * lse + (1.f - sb);
    float bsk = s_info[0];
    k_sumV[k] = t[0] * bsk;   // includes bs_k factor
    k_cnt[k] = cntT;
    k_bsk[k] = bsk;
    k_sumpl[k] = t[2];
    k_betapen[k] = beta_pen;
    #pragma unroll
    for (int c = 0; c < 8; ++c) k_xa[k * 8 + c] = s_xa[c];
  }
}

// ---------------- Kernel C: repulsion — direct point stream ----------------
// M_not[k] == all points of batch(k) with asso != k (noise included), so we
// iterate the batch's point range linearly (coalesced) instead of gathering
// through the 15.8 MB index matrix. N_kn = Nper - count_k (done in finalize).
__global__ __launch_bounds__(256) void rep_kernel(
    const float* __restrict__ coords, const float* __restrict__ bs,
    const int* __restrict__ asso, const float* __restrict__ k_xa,
    int Nper, int Kper, float* __restrict__ rep_part) {
  const int k = blockIdx.x / SPLIT;   // global cluster id
  const int s = blockIdx.x % SPLIT;
  const int b = k / Kper;             // batch
  const int chunk = (Nper + SPLIT - 1) / SPLIT;
  const int lo = b * Nper + s * chunk;
  const int hi = min(b * Nper + Nper, lo + chunk);
  float xa[8];
  #pragma unroll
  for (int c = 0; c < 8; ++c) xa[c] = k_xa[k * 8 + c];
  float srep = 0.f;
  for (int n = lo + threadIdx.x; n < hi; n += blockDim.x) {
    const float4* c4 = reinterpret_cast<const float4*>(coords) + (long)n * 2;
    float4 p0 = c4[0], p1 = c4[1];
    int a = asso[n];
    float d0 = p0.x-xa[0], d1 = p0.y-xa[1], d2 = p0.z-xa[2], d3 = p0.w-xa[3];
    float d4 = p1.x-xa[4], d5 = p1.y-xa[5], d6 = p1.z-xa[6], d7 = p1.w-xa[7];
    float dsq = d0*d0+d1*d1+d2*d2+d3*d3+d4*d4+d5*d5+d6*d6+d7*d7;
    float t = dsq + 1e-6f;
    if (t < 1.f && a != k) srep += (1.f - sqrtf(t)) * bs[n];
  }
  const int lane = threadIdx.x & 63, wid = threadIdx.x >> 6;
  __shared__ float red[4];
  for (int o = 32; o > 0; o >>= 1) srep += __shfl_down(srep, o, 64);
  if (lane == 0) red[wid] = srep;
  __syncthreads();
  if (threadIdx.x == 0)
    rep_part[k * SPLIT + s] = red[0] + red[1] + red[2] + red[3];
}

// ---------------- Kernel D: finalize scalars + per-k losses ----------------
__global__ __launch_bounds__(256) void finalize_kernel(
    const float* __restrict__ k_sumV, const float* __restrict__ k_cnt,
    const float* __restrict__ k_bsk, const float* __restrict__ k_betapen,
    const float* __restrict__ rep_part,
    const int* __restrict__ k_per_obj, const int* __restrict__ lengths,
    const float* __restrict__ noise,
    float* __restrict__ k_LVk, float* __restrict__ k_Lrepk,
    float* __restrict__ out, int K, int B, int Nper) {
  float lv = 0.f, lrep = 0.f, lb = 0.f;
  for (int k = threadIdx.x; k < K; k += blockDim.x) {
    float cnt = k_cnt[k];
    float LVk = k_sumV[k] / (cnt + 1e-6f);
    float sr = 0.f;
    for (int s = 0; s < SPLIT; ++s) sr += rep_part[k*SPLIT+s];
    float Nkn = (float)Nper - cnt;
    float Lrepk = k_bsk[k] * sr / (Nkn + 1e-6f);
    k_LVk[k] = LVk;
    k_Lrepk[k] = Lrepk;
    float invK = 1.f / (float)k_per_obj[k];
    lv += LVk * invK;
    lrep += Lrepk * invK;
    lb += k_betapen[k] * invK;
  }
  const int lane = threadIdx.x & 63, wid = threadIdx.x >> 6;
  __shared__ float red[3][4];
  float vals[3] = {lv, lrep, lb};
  #pragma unroll
  for (int j = 0; j < 3; ++j) {
    float v = vals[j];
    for (int o = 32; o > 0; o >>= 1) v += __shfl_down(v, o, 64);
    if (lane == 0) red[j][wid] = v;
  }
  __syncthreads();
  if (threadIdx.x == 0) {
    float lvT = red[0][0]+red[0][1]+red[0][2]+red[0][3];
    float lrT = red[1][0]+red[1][1]+red[1][2]+red[1][3];
    float lbT = red[2][0]+red[2][1]+red[2][2]+red[2][3];
    float noiseterm = 0.f;
    for (int b = 0; b < B; ++b) noiseterm += noise[b] / (float)lengths[b];
    noiseterm /= (float)B;
    out[0] = lvT;
    out[1] = lrT;
    out[2] = lbT + noiseterm;
  }
}

// ---------------- Kernel E: scatter per-point outputs ----------------------
__global__ __launch_bounds__(256) void scatter_kernel(
    const float* __restrict__ pl, const int* __restrict__ asso,
    const float* __restrict__ k_sumpl, const float* __restrict__ k_LVk,
    const float* __restrict__ k_Lrepk,
    float* __restrict__ out_pl, float* __restrict__ out_lvrep, int N) {
  int n = blockIdx.x * blockDim.x + threadIdx.x;
  if (n < N) {
    int a = asso[n];
    float op = 0.f, ol = 0.f;
    if (a >= 0) {
      op = pl[n] / (k_sumpl[a] + 1e-12f);
      ol = k_LVk[a] + k_Lrepk[a];
    }
    out_pl[n] = op;
    out_lvrep[n] = ol;
  }
}

extern "C" void kernel_launch(void* const* d_in, const int* in_sizes, int n_in,
                              void* d_out, int out_size, void* d_ws, size_t ws_size,
                              hipStream_t stream) {
  const float* beta      = (const float*)d_in[0];
  const float* coords    = (const float*)d_in[1];
  const int*   asso      = (const int*)d_in[2];
  const int*   M         = (const int*)d_in[3];
  const int*   k_per_obj = (const int*)d_in[5];
  const int*   rowidx    = (const int*)d_in[6];
  const int*   lengths   = (const int*)d_in[7];

  const int N    = in_sizes[0];
  const int K    = in_sizes[5];
  const int Mmax = in_sizes[3] / K;
  const int B    = in_sizes[7];
  const int Nper = N / B;
  const int Kper = K / B;

  float* ws        = (float*)d_ws;
  float* bs        = ws;                    // N
  float* pl        = bs + N;                // N
  float* k_sumV    = pl + N;                // K
  float* k_cnt     = k_sumV + K;            // K
  float* k_bsk     = k_cnt + K;             // K
  float* k_sumpl   = k_bsk + K;             // K
  float* k_betapen = k_sumpl + K;           // K
  float* k_xa      = k_betapen + K;         // K*8
  float* rep_part  = k_xa + K * 8;          // K*SPLIT
  float* k_LVk     = rep_part + K * SPLIT;  // K
  float* k_Lrepk   = k_LVk + K;             // K
  float* noise     = k_Lrepk + K;           // 16

  float* out       = (float*)d_out;
  float* out_pl    = out + 3;
  float* out_lvrep = out + 3 + N;

  hipMemsetAsync(noise, 0, 16 * sizeof(float), stream);

  int nb = (N + 255) / 256;
  prep_kernel<<<nb, 256, 0, stream>>>(beta, asso, rowidx, bs, pl, noise, N);
  cluster_kernel<<<K, 256, 0, stream>>>(beta, coords, bs, pl, M, Mmax,
                                        k_sumV, k_cnt, k_bsk, k_sumpl, k_betapen, k_xa);
  rep_kernel<<<K * SPLIT, 256, 0, stream>>>(coords, bs, asso, k_xa, Nper, Kper, rep_part);
  finalize_kernel<<<1, 256, 0, stream>>>(k_sumV, k_cnt, k_bsk, k_betapen, rep_part,
                                         k_per_obj, lengths, noise, k_LVk, k_Lrepk, out, K, B, Nper);
  scatter_kernel<<<nb, 256, 0, stream>>>(pl, asso, k_sumpl, k_LVk, k_Lrepk, out_pl, out_lvrep, N);
}

// Round 3
// 26.141 us; speedup vs baseline: 1.4681x; 1.3229x over previous
//
#include <hip/hip_runtime.h>
#include <hip/hip_bf16.h>
#include <math.h>

#define SPLIT 8
#define CL 4

constexpr float QMIN = 0.1f;
constexpr float EPS = 0.001f;   // EPS_LSE
constexpr float INV_BSE = 1.0f / 1.001f;

__device__ __forceinline__ float atanhsq(float b) {
  float a = atanhf(b * INV_BSE);
  return a * a;
}

// ---- Kernel 1: per-cluster member stats + repulsion stream, fused ---------
// grid = B * GPB * SPLIT blocks, 256 threads (4 waves).
// Wave w handles cluster c0+w's member phases (argmax -> x_a, member sums);
// then all waves stream chunk s of the batch's points against the group's
// CL condensation points at once.
__global__ __launch_bounds__(256) void fused_cluster_rep(
    const float* __restrict__ beta, const float* __restrict__ coords,
    const int* __restrict__ asso, const int* __restrict__ M,
    int Mmax, int Nper, int Kper, int GPB,
    float* __restrict__ k_sumV, float* __restrict__ k_cnt,
    float* __restrict__ k_bsk, float* __restrict__ k_sumpl,
    float* __restrict__ k_betapen,
    float* __restrict__ rep_part, float* __restrict__ noise_part) {
  const int G = blockIdx.x / SPLIT, s = blockIdx.x % SPLIT;
  const int b = G / GPB, gi = G % GPB;
  const int c0 = b * Kper + gi * CL;
  const int ncl = min(CL, Kper - gi * CL);
  const int w = threadIdx.x >> 6, lane = threadIdx.x & 63;

  __shared__ float s_xa[CL][8];
  __shared__ float red[CL][4];
  __shared__ float redn[4];

  if (w < ncl) {
    const int k = c0 + w;
    const int* Mrow = M + (long)k * Mmax;

    // phase 1: argmax of beta_scale over members (first-index tiebreak), max beta
    float bestV = -1.f; int bestI = 0x7fffffff; float maxb = 0.f;
    for (int i = lane; i < Mmax; i += 64) {
      int idx = Mrow[i];
      if (idx >= 0) {
        float bb = beta[idx];
        float v = atanhsq(bb) + QMIN;
        if (v > bestV || (v == bestV && i < bestI)) { bestV = v; bestI = i; }
        maxb = fmaxf(maxb, bb);
      }
    }
    #pragma unroll
    for (int o = 1; o < 64; o <<= 1) {
      float v2 = __shfl_xor(bestV, o, 64);
      int   i2 = __shfl_xor(bestI, o, 64);
      float m2 = __shfl_xor(maxb, o, 64);
      if (v2 > bestV || (v2 == bestV && i2 < bestI)) { bestV = v2; bestI = i2; }
      maxb = fmaxf(maxb, m2);
    }
    int alpha = Mrow[bestI];                       // same addr all lanes: broadcast
    const float4* ca = reinterpret_cast<const float4*>(coords) + (long)alpha * 2;
    float4 a0 = ca[0], a1 = ca[1];
    float xa[8] = {a0.x, a0.y, a0.z, a0.w, a1.x, a1.y, a1.z, a1.w};

    // phase 2: member sums
    float sumV = 0.f, cnt = 0.f, sumpl = 0.f, sumbeta = 0.f, sumexp = 0.f;
    for (int i = lane; i < Mmax; i += 64) {
      int idx = Mrow[i];
      if (idx >= 0) {
        const float4* c4 = reinterpret_cast<const float4*>(coords) + (long)idx * 2;
        float4 p0 = c4[0], p1 = c4[1];
        float bb = beta[idx];
        float p = atanhsq(bb);
        float d0 = p0.x-xa[0], d1 = p0.y-xa[1], d2 = p0.z-xa[2], d3 = p0.w-xa[3];
        float d4 = p1.x-xa[4], d5 = p1.y-xa[5], d6 = p1.z-xa[6], d7 = p1.w-xa[7];
        float dsq = d0*d0+d1*d1+d2*d2+d3*d3+d4*d4+d5*d5+d6*d6+d7*d7;
        sumV += dsq * (p + QMIN);
        cnt  += 1.f;
        sumpl += p;
        sumbeta += bb;
        sumexp += expf((bb - maxb) * (1.f / EPS));
      }
    }
    float vals[5] = {sumV, cnt, sumpl, sumbeta, sumexp};
    #pragma unroll
    for (int j = 0; j < 5; ++j) {
      float v = vals[j];
      #pragma unroll
      for (int o = 32; o > 0; o >>= 1) v += __shfl_down(v, o, 64);
      vals[j] = v;
    }
    if (lane < 8) s_xa[w][lane] = xa[lane];
    if (lane == 0 && s == 0) {
      float cntT = vals[1];
      float npad = (float)Mmax - cntT;              // zero-padded lse entries
      float sumexpT = vals[4] + npad * expf(-maxb * (1.f / EPS));
      float lse = maxb * (1.f / EPS) + logf(sumexpT);
      float sb = fminf(fmaxf(vals[3], 0.f), 1.f);
      k_betapen[k] = 1.f - EPS * lse + (1.f - sb);
      k_sumV[k]  = vals[0] * bestV;                 // includes bs_k factor
      k_cnt[k]   = cntT;
      k_bsk[k]   = bestV;                           // bs at alpha == argmax value
      k_sumpl[k] = vals[2];
    }
  } else {
    if (lane < 8) s_xa[w][lane] = 0.f;              // keep stream math finite
  }
  __syncthreads();

  // phase 3: stream this batch's point chunk against CL condensation points
  float xav[CL][8];
  #pragma unroll
  for (int c = 0; c < CL; ++c)
    #pragma unroll
    for (int j = 0; j < 8; ++j) xav[c][j] = s_xa[c][j];

  const int chunk = (Nper + SPLIT - 1) / SPLIT;
  const int lo = b * Nper + s * chunk;
  const int hi = min(b * Nper + Nper, lo + chunk);
  const bool donoise = (gi == 0);

  float srep[CL] = {0.f, 0.f, 0.f, 0.f};
  float snoise = 0.f;
  for (int n = lo + threadIdx.x; n < hi; n += 256) {
    const float4* c4 = reinterpret_cast<const float4*>(coords) + (long)n * 2;
    float4 p0 = c4[0], p1 = c4[1];
    int a = asso[n];
    float bsn = -1.f;
    #pragma unroll
    for (int c = 0; c < CL; ++c) {
      float d0 = p0.x-xav[c][0], d1 = p0.y-xav[c][1], d2 = p0.z-xav[c][2], d3 = p0.w-xav[c][3];
      float d4 = p1.x-xav[c][4], d5 = p1.y-xav[c][5], d6 = p1.z-xav[c][6], d7 = p1.w-xav[c][7];
      float dsq = d0*d0+d1*d1+d2*d2+d3*d3+d4*d4+d5*d5+d6*d6+d7*d7;
      float t = dsq + 1e-6f;
      if (t < 1.f && c < ncl && a != c0 + c) {
        if (bsn < 0.f) bsn = atanhsq(beta[n]) + QMIN;
        srep[c] += (1.f - sqrtf(t)) * bsn;
      }
    }
    if (donoise && a < 0) snoise += beta[n];
  }

  #pragma unroll
  for (int c = 0; c < CL; ++c) {
    float v = srep[c];
    #pragma unroll
    for (int o = 32; o > 0; o >>= 1) v += __shfl_down(v, o, 64);
    if (lane == 0) red[c][w] = v;
  }
  #pragma unroll
  for (int o = 32; o > 0; o >>= 1) snoise += __shfl_down(snoise, o, 64);
  if (lane == 0) redn[w] = snoise;
  __syncthreads();
  if (threadIdx.x == 0) {
    for (int c = 0; c < ncl; ++c)
      rep_part[(c0 + c) * SPLIT + s] = red[c][0] + red[c][1] + red[c][2] + red[c][3];
    if (donoise) noise_part[b * SPLIT + s] = redn[0] + redn[1] + redn[2] + redn[3];
  }
}

// ---- Kernel 2: finalize scalars + scatter per-point outputs ---------------
__global__ __launch_bounds__(256) void out_kernel(
    const float* __restrict__ beta, const int* __restrict__ asso,
    const float* __restrict__ k_sumV, const float* __restrict__ k_cnt,
    const float* __restrict__ k_bsk, const float* __restrict__ k_sumpl,
    const float* __restrict__ k_betapen,
    const float* __restrict__ rep_part, const float* __restrict__ noise_part,
    const int* __restrict__ k_per_obj, const int* __restrict__ lengths,
    int K, int B, int Nper, int N, int nb, float* __restrict__ out) {
  if (blockIdx.x == (unsigned)nb) {
    // scalar losses
    float lv = 0.f, lrep = 0.f, lb = 0.f;
    for (int k = threadIdx.x; k < K; k += 256) {
      float cnt = k_cnt[k];
      float sr = 0.f;
      #pragma unroll
      for (int ss = 0; ss < SPLIT; ++ss) sr += rep_part[k * SPLIT + ss];
      float LVk   = k_sumV[k] / (cnt + 1e-6f);
      float Lrepk = k_bsk[k] * sr / ((float)Nper - cnt + 1e-6f);
      float invK  = 1.f / (float)k_per_obj[k];
      lv   += LVk * invK;
      lrep += Lrepk * invK;
      lb   += k_betapen[k] * invK;
    }
    const int lane = threadIdx.x & 63, w = threadIdx.x >> 6;
    __shared__ float red[3][4];
    float vals[3] = {lv, lrep, lb};
    #pragma unroll
    for (int j = 0; j < 3; ++j) {
      float v = vals[j];
      #pragma unroll
      for (int o = 32; o > 0; o >>= 1) v += __shfl_down(v, o, 64);
      if (lane == 0) red[j][w] = v;
    }
    __syncthreads();
    if (threadIdx.x == 0) {
      float noiseterm = 0.f;
      for (int bb = 0; bb < B; ++bb) {
        float npb = 0.f;
        for (int ss = 0; ss < SPLIT; ++ss) npb += noise_part[bb * SPLIT + ss];
        noiseterm += npb / (float)lengths[bb];
      }
      noiseterm /= (float)B;
      out[0] = red[0][0] + red[0][1] + red[0][2] + red[0][3];
      out[1] = red[1][0] + red[1][1] + red[1][2] + red[1][3];
      out[2] = red[2][0] + red[2][1] + red[2][2] + red[2][3] + noiseterm;
    }
  } else {
    int n = blockIdx.x * 256 + threadIdx.x;
    if (n < N) {
      int a = asso[n];
      float op = 0.f, ol = 0.f;
      if (a >= 0) {
        float p = atanhsq(beta[n]);
        op = p / (k_sumpl[a] + 1e-12f);
        float cnt = k_cnt[a];
        float sr = 0.f;
        #pragma unroll
        for (int ss = 0; ss < SPLIT; ++ss) sr += rep_part[a * SPLIT + ss];
        ol = k_sumV[a] / (cnt + 1e-6f)
           + k_bsk[a] * sr / ((float)Nper - cnt + 1e-6f);
      }
      out[3 + n] = op;
      out[3 + N + n] = ol;
    }
  }
}

extern "C" void kernel_launch(void* const* d_in, const int* in_sizes, int n_in,
                              void* d_out, int out_size, void* d_ws, size_t ws_size,
                              hipStream_t stream) {
  const float* beta      = (const float*)d_in[0];
  const float* coords    = (const float*)d_in[1];
  const int*   asso      = (const int*)d_in[2];
  const int*   M         = (const int*)d_in[3];
  const int*   k_per_obj = (const int*)d_in[5];
  const int*   lengths   = (const int*)d_in[7];

  const int N    = in_sizes[0];
  const int K    = in_sizes[5];
  const int Mmax = in_sizes[3] / K;
  const int B    = in_sizes[7];
  const int Nper = N / B;
  const int Kper = K / B;
  const int GPB  = (Kper + CL - 1) / CL;

  float* ws        = (float*)d_ws;
  float* k_sumV    = ws;                     // K
  float* k_cnt     = k_sumV + K;             // K
  float* k_bsk     = k_cnt + K;              // K
  float* k_sumpl   = k_bsk + K;              // K
  float* k_betapen = k_sumpl + K;            // K
  float* rep_part  = k_betapen + K;          // K*SPLIT
  float* noise_part= rep_part + K * SPLIT;   // B*SPLIT

  float* out = (float*)d_out;

  const int grid1 = B * GPB * SPLIT;
  fused_cluster_rep<<<grid1, 256, 0, stream>>>(
      beta, coords, asso, M, Mmax, Nper, Kper, GPB,
      k_sumV, k_cnt, k_bsk, k_sumpl, k_betapen, rep_part, noise_part);

  const int nb = (N + 255) / 256;
  out_kernel<<<nb + 1, 256, 0, stream>>>(
      beta, asso, k_sumV, k_cnt, k_bsk, k_sumpl, k_betapen,
      rep_part, noise_part, k_per_obj, lengths, K, B, Nper, N, nb, out);
}